// Round 2
// baseline (89.244 us; speedup 1.0000x reference)
//
#include <hip/hip_runtime.h>

#define B 16384
#define C 4
#define M 512
#define D 512
#define NCH 16

// ---------------- K0: zero the candidate counter ---------------------------
__global__ void k0_zero(int* __restrict__ nCand)
{
    if (threadIdx.x == 0) *nCand = 0;
}

// ---------------- K1: softmax / entropy / argmax + candidate build ---------
__global__ __launch_bounds__(256) void k1_stats(
    const float* __restrict__ logits,
    const float* __restrict__ ent_memo,
    float* __restrict__ out,
    int* __restrict__ kbFlag,
    int* __restrict__ rnkB,
    int* __restrict__ rnkM,
    uint2* __restrict__ candList,
    int* __restrict__ nCand)
{
    int b = blockIdx.x * 256 + threadIdx.x;
    float4 l = *reinterpret_cast<const float4*>(logits + (size_t)b * 4);
    float m = l.x; int idx = 0;
    if (l.y > m) { m = l.y; idx = 1; }
    if (l.z > m) { m = l.z; idx = 2; }
    if (l.w > m) { m = l.w; idx = 3; }
    float e0 = expf(l.x - m), e1 = expf(l.y - m), e2 = expf(l.z - m), e3 = expf(l.w - m);
    float s = e0 + e1 + e2 + e3;
    float inv = 1.0f / s;
    float p0 = e0 * inv, p1 = e1 * inv, p2 = e2 * inv, p3 = e3 * inv;
    float lse = logf(s);
    float ent = -(p0 * (l.x - m - lse) + p1 * (l.y - m - lse)
                + p2 * (l.z - m - lse) + p3 * (l.w - m - lse));
    float4 pr = { p0, p1, p2, p3 };
    *reinterpret_cast<float4*>(out + (size_t)B * 4 + (size_t)b * 4) = pr;
    out[(size_t)B * 8 + b] = ent;
    kbFlag[b] = 0;
    rnkB[b] = 0;
    if (b < C * M) rnkM[b] = 0;

    const float* Ac = ent_memo + (idx << 9);
    float amax = Ac[M - 1];
    if (ent < amax) {
        int lo = 0, hi = M;                 // upper_bound -> #{A <= ent}
        while (lo < hi) { int mid = (lo + hi) >> 1; if (Ac[mid] <= ent) lo = mid + 1; else hi = mid; }
        int pos = atomicAdd(nCand, 1);
        if (pos < B)
            candList[pos] = make_uint2(__float_as_uint(ent),
                ((unsigned)lo << 16) | ((unsigned)idx << 14) | (unsigned)b);
    }
}

// ---------------- K2a: partial pairwise rank counts (2-D split) ------------
__global__ __launch_bounds__(256) void k2a_count(
    const float* __restrict__ ent_memo,
    const uint2* __restrict__ candList,
    const int* __restrict__ nCandP,
    int* __restrict__ rnkB,
    int* __restrict__ rnkM)
{
    __shared__ uint2 ch[(B + NCH - 1) / NCH];     // 1024 entries = 8 KB
    int n = *nCandP; if (n > B) n = B;
    int t = blockIdx.x * 256 + threadIdx.x;
    int nRole = n > C * M ? n : C * M;
    if (blockIdx.x * 256 >= nRole) return;        // uniform: whole block
    int ck = (n + NCH - 1) / NCH;
    int base = blockIdx.y * ck;
    int cnt = n - base; if (cnt > ck) cnt = ck;
    if (cnt <= 0) return;                         // uniform: whole block

    for (int i = threadIdx.x; i < cnt; i += 256) ch[i] = candList[base + i];
    __syncthreads();

    bool candRole = t < n;
    float e = 0.0f; int lab = -1, bidx = 0;
    if (candRole) {
        uint2 v = candList[t];
        e = __uint_as_float(v.x);
        lab = (int)((v.y >> 14) & 3);
        bidx = (int)(v.y & 0x3FFF);
    }
    bool memoRole = t < C * M;
    int mc = t >> 9;
    float Am = 0.0f;
    if (memoRole) Am = ent_memo[t];

    int r = 0, rm = 0;
    for (int i = 0; i < cnt; i++) {
        uint2 v = ch[i];
        float e2 = __uint_as_float(v.x);
        int l2 = (int)((v.y >> 14) & 3);
        if (candRole && l2 == lab) {
            if (e2 < e) r++;
            else if (e2 == e && (int)(v.y & 0x3FFF) < bidx) r++;
        }
        if (memoRole && l2 == mc && e2 < Am) rm++;
    }
    if (candRole && r) atomicAdd(&rnkB[t], r);
    if (memoRole && rm) atomicAdd(&rnkM[t], rm);
}

// ---------------- K2b: flags + deterministic compaction --------------------
__global__ __launch_bounds__(256) void k2b_compact(
    const uint2* __restrict__ candList,
    const int* __restrict__ nCandP,
    const int* __restrict__ rnkB,
    const int* __restrict__ rnkM,
    int* __restrict__ kbFlag,
    int* __restrict__ list)
{
    __shared__ int Kc[C];
    __shared__ int s0[256], s1[256], s2[256], s3[256];
    int t = threadIdx.x;
    int n = *nCandP; if (n > B) n = B;

    for (int i = t; i < C * M; i += 256) list[i] = 0;   // defensive prefill
    if (t < C) Kc[t] = 0;
    __syncthreads();

    // batch kept flags (value = 1 + label)
    for (int i = t; i < n; i += 256) {
        uint2 v = candList[i];
        int lo = (int)(v.y >> 16);
        if (lo + rnkB[i] < M)
            kbFlag[v.y & 0x3FFF] = 1 + (int)((v.y >> 14) & 3);
    }
    // memo kept counts
    for (int i = t; i < C * M; i += 256)
        if ((i & (M - 1)) + rnkM[i] < M) atomicAdd(&Kc[i >> 9], 1);
    __syncthreads();

    // memo part of the list: kept memo rows are exactly the prefix [0, Kc)
    for (int i = t; i < C * M; i += 256) {
        int c = i >> 9, j = i & (M - 1);
        if (j < Kc[c]) list[i] = j;
    }

    // batch part: per-thread counts, block scan, scatter (order = b ascending)
    int c0 = 0, c1 = 0, c2 = 0, c3 = 0;
    int b0 = t * 64;
    for (int k = 0; k < 64; k++) {
        int fb = kbFlag[b0 + k];
        if (fb) {
            int c = fb - 1;
            if (c == 0) c0++; else if (c == 1) c1++; else if (c == 2) c2++; else c3++;
        }
    }
    s0[t] = c0; s1[t] = c1; s2[t] = c2; s3[t] = c3;
    __syncthreads();
    for (int off = 1; off < 256; off <<= 1) {
        int a0 = s0[t], a1 = s1[t], a2 = s2[t], a3 = s3[t];
        int u0 = 0, u1 = 0, u2 = 0, u3 = 0;
        if (t >= off) { u0 = s0[t - off]; u1 = s1[t - off]; u2 = s2[t - off]; u3 = s3[t - off]; }
        __syncthreads();
        s0[t] = a0 + u0; s1[t] = a1 + u1; s2[t] = a2 + u2; s3[t] = a3 + u3;
        __syncthreads();
    }
    int o0 = Kc[0] + s0[t] - c0;
    int o1 = Kc[1] + s1[t] - c1;
    int o2 = Kc[2] + s2[t] - c2;
    int o3 = Kc[3] + s3[t] - c3;
    for (int k = 0; k < 64; k++) {
        int b = b0 + k;
        int fb = kbFlag[b];
        if (fb) {
            int c = fb - 1;
            int pos;
            if (c == 0) pos = o0++; else if (c == 1) pos = o1++; else if (c == 2) pos = o2++; else pos = o3++;
            list[(c << 9) + (pos & (M - 1))] = 0x10000 | b;
        }
    }
}

// ---------------- K4: partial row-sums of the kept rows --------------------
__global__ __launch_bounds__(256) void k4_partial(
    const int* __restrict__ list,
    const float* __restrict__ text_memo,
    const float* __restrict__ text_embeds,
    float* __restrict__ part)
{
    int blk = blockIdx.x;              // 128 blocks: c = blk>>5, seg = blk&31
    int c = blk >> 5, seg = blk & 31;
    int t = threadIdx.x;
    __shared__ int le[16];
    if (t < 16) le[t] = list[(c << 9) + seg * 16 + t];
    __syncthreads();
    float a0 = 0.0f, a1 = 0.0f;
    for (int j = 0; j < 16; j++) {
        int e = le[j];
        const float* row = (e & 0x10000)
            ? (text_embeds + (size_t)(e & 0x3FFF) * D)
            : (text_memo + (size_t)((c << 9) | (e & (M - 1))) * D);
        a0 += row[t];
        a1 += row[t + 256];
    }
    part[(size_t)blk * D + t] = a0;
    part[(size_t)blk * D + t + 256] = a1;
}

__global__ __launch_bounds__(256) void k4c_reduce(
    const float* __restrict__ part, float* __restrict__ S)
{
    int t = blockIdx.x * 256 + threadIdx.x;   // 2048 threads: (c,d)
    int c = t >> 9, d = t & (D - 1);
    float s = 0.0f;
    for (int seg = 0; seg < 32; seg++) s += part[(size_t)((c << 5) + seg) * D + d];
    S[t] = s;
}

// ---------------- K5: cosin GEMV + combines + 2-way softmaxes --------------
__global__ __launch_bounds__(256) void k5_cosin(
    const float* __restrict__ text_embeds,
    const float* __restrict__ S,
    float* __restrict__ out)
{
    __shared__ float Sl[C * D];
    int t = threadIdx.x;
    for (int i = t; i < C * D; i += 256) Sl[i] = S[i];
    __syncthreads();
    int wave = t >> 6, lane = t & 63;
    for (int r = 0; r < 4; r++) {
        int b = blockIdx.x * 16 + wave * 4 + r;
        float c0 = 0.0f, c1 = 0.0f, c2 = 0.0f, c3 = 0.0f;
        for (int k = 0; k < 8; k++) {
            int di = k * 64 + lane;
            float tv = text_embeds[(size_t)b * D + di];
            c0 += tv * Sl[di];
            c1 += tv * Sl[D + di];
            c2 += tv * Sl[2 * D + di];
            c3 += tv * Sl[3 * D + di];
        }
        for (int off = 32; off; off >>= 1) {
            c0 += __shfl_down(c0, off, 64);
            c1 += __shfl_down(c1, off, 64);
            c2 += __shfl_down(c2, off, 64);
            c3 += __shfl_down(c3, off, 64);
        }
        if (lane == 0) {
            float t0 = c0 + c2, t1 = c1 + c3;   // text_combine
            float v0 = c0 + c1, v1 = c2 + c3;   // vision_combine
            float tm = fmaxf(t0, t1);
            float te0 = expf(t0 - tm), te1 = expf(t1 - tm);
            float ts = te0 + te1;
            float mt0 = te0 / ts, mt1 = te1 / ts;
            float vm = fmaxf(v0, v1);
            float ve0 = expf(v0 - vm), ve1 = expf(v1 - vm);
            float vs = ve0 + ve1;
            float mv0 = ve0 / vs, mv1 = ve1 / vs;
            float4 o = { mt0 * mv0, mt1 * mv0, mt0 * mv1, mt1 * mv1 };
            *reinterpret_cast<float4*>(out + (size_t)b * 4) = o;
        }
    }
}

// ---------------------------------------------------------------------------
extern "C" void kernel_launch(void* const* d_in, const int* in_sizes, int n_in,
                              void* d_out, int out_size, void* d_ws, size_t ws_size,
                              hipStream_t stream)
{
    (void)in_sizes; (void)n_in; (void)out_size; (void)ws_size;
    const float* logits      = (const float*)d_in[0];
    const float* text_embeds = (const float*)d_in[1];
    const float* ent_memo    = (const float*)d_in[3];
    const float* text_memo   = (const float*)d_in[4];
    float* out = (float*)d_out;
    char* ws = (char*)d_ws;

    // workspace layout (bytes)
    int*   nCand    = (int*)(ws + 0);          // 4 B (pad 256)
    uint2* candList = (uint2*)(ws + 256);      // 128 KB          -> 131328
    int*   rnkB     = (int*)(ws + 131328);     // 64 KB           -> 196864
    int*   rnkM     = (int*)(ws + 196864);     // 8 KB            -> 205056
    int*   kbFlag   = (int*)(ws + 205056);     // 64 KB           -> 270592
    int*   list     = (int*)(ws + 270592);     // 8 KB            -> 278784
    float* part     = (float*)(ws + 278784);   // 256 KB          -> 540928
    float* S        = (float*)(ws + 540928);   // 8 KB            -> 549120

    k0_zero<<<1, 64, 0, stream>>>(nCand);
    k1_stats<<<B / 256, 256, 0, stream>>>(logits, ent_memo, out, kbFlag, rnkB, rnkM, candList, nCand);
    k2a_count<<<dim3(B / 256, NCH), 256, 0, stream>>>(ent_memo, candList, nCand, rnkB, rnkM);
    k2b_compact<<<1, 256, 0, stream>>>(candList, nCand, rnkB, rnkM, kbFlag, list);
    k4_partial<<<128, 256, 0, stream>>>(list, text_memo, text_embeds, part);
    k4c_reduce<<<8, 256, 0, stream>>>(part, S);
    k5_cosin<<<B / 16, 256, 0, stream>>>(text_embeds, S, out);
}

// Round 3
// 58.698 us; speedup vs baseline: 1.5204x; 1.5204x over previous
//
#include <hip/hip_runtime.h>

#define B 16384
#define C 4
#define M 512
#define D 512
#define NCH 16

// ---------------- K0: zero the candidate counter ---------------------------
__global__ void k0_zero(int* __restrict__ nCand)
{
    if (threadIdx.x == 0) *nCand = 0;
}

// ---------------- K1: softmax / entropy / argmax + candidate build ---------
__global__ __launch_bounds__(256) void k1_stats(
    const float* __restrict__ logits,
    const float* __restrict__ ent_memo,
    float* __restrict__ out,
    int* __restrict__ rnkB,
    int* __restrict__ rnkM,
    uint2* __restrict__ candList,
    int* __restrict__ nCand)
{
    int b = blockIdx.x * 256 + threadIdx.x;
    float4 l = *reinterpret_cast<const float4*>(logits + (size_t)b * 4);
    float m = l.x; int idx = 0;
    if (l.y > m) { m = l.y; idx = 1; }
    if (l.z > m) { m = l.z; idx = 2; }
    if (l.w > m) { m = l.w; idx = 3; }
    float e0 = expf(l.x - m), e1 = expf(l.y - m), e2 = expf(l.z - m), e3 = expf(l.w - m);
    float s = e0 + e1 + e2 + e3;
    float inv = 1.0f / s;
    float p0 = e0 * inv, p1 = e1 * inv, p2 = e2 * inv, p3 = e3 * inv;
    float lse = logf(s);
    float ent = -(p0 * (l.x - m - lse) + p1 * (l.y - m - lse)
                + p2 * (l.z - m - lse) + p3 * (l.w - m - lse));
    float4 pr = { p0, p1, p2, p3 };
    *reinterpret_cast<float4*>(out + (size_t)B * 4 + (size_t)b * 4) = pr;
    out[(size_t)B * 8 + b] = ent;
    rnkB[b] = 0;
    if (b < C * M) rnkM[b] = 0;

    const float* Ac = ent_memo + (idx << 9);
    float amax = Ac[M - 1];
    if (ent < amax) {
        int lo = 0, hi = M;                 // upper_bound -> #{A <= ent}
        while (lo < hi) { int mid = (lo + hi) >> 1; if (Ac[mid] <= ent) lo = mid + 1; else hi = mid; }
        int pos = atomicAdd(nCand, 1);
        if (pos < B)
            candList[pos] = make_uint2(__float_as_uint(ent),
                ((unsigned)lo << 16) | ((unsigned)idx << 14) | (unsigned)b);
    }
}

// ---------------- K2a: partial pairwise rank counts (2-D split) ------------
__global__ __launch_bounds__(256) void k2a_count(
    const float* __restrict__ ent_memo,
    const uint2* __restrict__ candList,
    const int* __restrict__ nCandP,
    int* __restrict__ rnkB,
    int* __restrict__ rnkM)
{
    __shared__ uint2 ch[B / NCH];                 // 1024 entries = 8 KB
    int n = *nCandP; if (n > B) n = B;
    int t = blockIdx.x * 256 + threadIdx.x;
    int nRole = n > C * M ? n : C * M;
    if (blockIdx.x * 256 >= nRole) return;        // uniform: whole block
    int ck = (n + NCH - 1) / NCH;
    int base = blockIdx.y * ck;
    int cnt = n - base; if (cnt > ck) cnt = ck;
    if (cnt <= 0) return;                         // uniform: whole block

    for (int i = threadIdx.x; i < cnt; i += 256) ch[i] = candList[base + i];
    __syncthreads();

    bool candRole = t < n;
    float e = 0.0f; int lab = -1, bidx = 0;
    if (candRole) {
        uint2 v = candList[t];
        e = __uint_as_float(v.x);
        lab = (int)((v.y >> 14) & 3);
        bidx = (int)(v.y & 0x3FFF);
    }
    bool memoRole = t < C * M;
    int mc = t >> 9;
    float Am = 0.0f;
    if (memoRole) Am = ent_memo[t];

    int r = 0, rm = 0;
    for (int i = 0; i < cnt; i++) {
        uint2 v = ch[i];
        float e2 = __uint_as_float(v.x);
        int l2 = (int)((v.y >> 14) & 3);
        if (candRole && l2 == lab) {
            if (e2 < e) r++;
            else if (e2 == e && (int)(v.y & 0x3FFF) < bidx) r++;
        }
        if (memoRole && l2 == mc && e2 < Am) rm++;
    }
    if (candRole && r) atomicAdd(&rnkB[t], r);
    if (memoRole && rm) atomicAdd(&rnkM[t], rm);
}

// ---------------- K2b: rank-bijection scatter (fully parallel) -------------
// Stable merged rank of memo row i  = i + rnkM[i]
// Stable merged rank of batch cand  = lo + rnkB[t]
// Kept set == ranks [0, M); ranks are a bijection -> direct scatter, no scan.
__global__ __launch_bounds__(256) void k2b_scatter(
    const uint2* __restrict__ candList,
    const int* __restrict__ nCandP,
    const int* __restrict__ rnkB,
    const int* __restrict__ rnkM,
    int* __restrict__ list)
{
    int t = blockIdx.x * 256 + threadIdx.x;
    int n = *nCandP; if (n > B) n = B;
    if (t < C * M) {
        int r = (t & (M - 1)) + rnkM[t];
        if (r < M) list[(t & ~(M - 1)) + r] = t & (M - 1);
    }
    if (t < n) {
        uint2 v = candList[t];
        int r = (int)(v.y >> 16) + rnkB[t];
        if (r < M) list[(((v.y >> 14) & 3) << 9) + r] = 0x10000 | (int)(v.y & 0x3FFF);
    }
}

// ---------------- K4: partial row-sums of the kept rows --------------------
__global__ __launch_bounds__(256) void k4_partial(
    const int* __restrict__ list,
    const float* __restrict__ text_memo,
    const float* __restrict__ text_embeds,
    float* __restrict__ part)
{
    int blk = blockIdx.x;              // 128 blocks: c = blk>>5, seg = blk&31
    int c = blk >> 5, seg = blk & 31;
    int t = threadIdx.x;
    __shared__ int le[16];
    if (t < 16) le[t] = list[(c << 9) + seg * 16 + t];
    __syncthreads();
    float a0 = 0.0f, a1 = 0.0f;
    for (int j = 0; j < 16; j++) {
        int e = le[j];
        const float* row = (e & 0x10000)
            ? (text_embeds + (size_t)(e & 0x3FFF) * D)
            : (text_memo + (size_t)((c << 9) | (e & (M - 1))) * D);
        a0 += row[t];
        a1 += row[t + 256];
    }
    part[(size_t)blk * D + t] = a0;
    part[(size_t)blk * D + t + 256] = a1;
}

__global__ __launch_bounds__(256) void k4c_reduce(
    const float* __restrict__ part, float* __restrict__ S)
{
    int t = blockIdx.x * 256 + threadIdx.x;   // 2048 threads: (c,d)
    int c = t >> 9, d = t & (D - 1);
    float s = 0.0f;
    for (int seg = 0; seg < 32; seg++) s += part[(size_t)((c << 5) + seg) * D + d];
    S[t] = s;
}

// ---------------- K5: cosin GEMV + combines + 2-way softmaxes --------------
__global__ __launch_bounds__(256) void k5_cosin(
    const float* __restrict__ text_embeds,
    const float* __restrict__ S,
    float* __restrict__ out)
{
    __shared__ float Sl[C * D];
    int t = threadIdx.x;
    for (int i = t; i < C * D; i += 256) Sl[i] = S[i];
    __syncthreads();
    int wave = t >> 6, lane = t & 63;
    for (int r = 0; r < 4; r++) {
        int b = blockIdx.x * 16 + wave * 4 + r;
        float c0 = 0.0f, c1 = 0.0f, c2 = 0.0f, c3 = 0.0f;
        for (int k = 0; k < 8; k++) {
            int di = k * 64 + lane;
            float tv = text_embeds[(size_t)b * D + di];
            c0 += tv * Sl[di];
            c1 += tv * Sl[D + di];
            c2 += tv * Sl[2 * D + di];
            c3 += tv * Sl[3 * D + di];
        }
        for (int off = 32; off; off >>= 1) {
            c0 += __shfl_down(c0, off, 64);
            c1 += __shfl_down(c1, off, 64);
            c2 += __shfl_down(c2, off, 64);
            c3 += __shfl_down(c3, off, 64);
        }
        if (lane == 0) {
            float t0 = c0 + c2, t1 = c1 + c3;   // text_combine
            float v0 = c0 + c1, v1 = c2 + c3;   // vision_combine
            float tm = fmaxf(t0, t1);
            float te0 = expf(t0 - tm), te1 = expf(t1 - tm);
            float ts = te0 + te1;
            float mt0 = te0 / ts, mt1 = te1 / ts;
            float vm = fmaxf(v0, v1);
            float ve0 = expf(v0 - vm), ve1 = expf(v1 - vm);
            float vs = ve0 + ve1;
            float mv0 = ve0 / vs, mv1 = ve1 / vs;
            float4 o = { mt0 * mv0, mt1 * mv0, mt0 * mv1, mt1 * mv1 };
            *reinterpret_cast<float4*>(out + (size_t)b * 4) = o;
        }
    }
}

// ---------------------------------------------------------------------------
extern "C" void kernel_launch(void* const* d_in, const int* in_sizes, int n_in,
                              void* d_out, int out_size, void* d_ws, size_t ws_size,
                              hipStream_t stream)
{
    (void)in_sizes; (void)n_in; (void)out_size; (void)ws_size;
    const float* logits      = (const float*)d_in[0];
    const float* text_embeds = (const float*)d_in[1];
    const float* ent_memo    = (const float*)d_in[3];
    const float* text_memo   = (const float*)d_in[4];
    float* out = (float*)d_out;
    char* ws = (char*)d_ws;

    // workspace layout (bytes)
    int*   nCand    = (int*)(ws + 0);          // 4 B (pad 256)
    uint2* candList = (uint2*)(ws + 256);      // 128 KB          -> 131328
    int*   rnkB     = (int*)(ws + 131328);     // 64 KB           -> 196864
    int*   rnkM     = (int*)(ws + 196864);     // 8 KB            -> 205056
    int*   list     = (int*)(ws + 205056);     // 8 KB            -> 213248
    float* part     = (float*)(ws + 213248);   // 256 KB          -> 475392
    float* S        = (float*)(ws + 475392);   // 8 KB            -> 483584

    k0_zero<<<1, 64, 0, stream>>>(nCand);
    k1_stats<<<B / 256, 256, 0, stream>>>(logits, ent_memo, out, rnkB, rnkM, candList, nCand);
    k2a_count<<<dim3(B / 256, NCH), 256, 0, stream>>>(ent_memo, candList, nCand, rnkB, rnkM);
    k2b_scatter<<<B / 256, 256, 0, stream>>>(candList, nCand, rnkB, rnkM, list);
    k4_partial<<<128, 256, 0, stream>>>(list, text_memo, text_embeds, part);
    k4c_reduce<<<8, 256, 0, stream>>>(part, S);
    k5_cosin<<<B / 16, 256, 0, stream>>>(text_embeds, S, out);
}